// Round 1
// 271.182 us; speedup vs baseline: 1.0349x; 1.0349x over previous
//
#include <hip/hip_runtime.h>
#include <hip/hip_bf16.h>
#include <type_traits>
#include <cstdint>

// Problem constants
#define IN_DIM   512
#define OUT_DIM  1024
#define MROWS    32768    // 8 * 4096

typedef float f32x4 __attribute__((ext_vector_type(4)));
typedef short s8vec __attribute__((ext_vector_type(8)));
typedef __bf16 b8vec __attribute__((ext_vector_type(8)));

template <typename V, typename = void>
struct mfma_ok : std::false_type {};
template <typename V>
struct mfma_ok<V, std::void_t<decltype(__builtin_amdgcn_mfma_f32_16x16x32_bf16(
    std::declval<V>(), std::declval<V>(), std::declval<f32x4>(), 0, 0, 0))>>
    : std::true_type {};
using frag_t = std::conditional_t<mfma_ok<s8vec>::value, s8vec, b8vec>;

__device__ __forceinline__ void async_copy16(void* lds, const void* g) {
    __builtin_amdgcn_global_load_lds(
        (const __attribute__((address_space(1))) void*)(uintptr_t)g,
        (__attribute__((address_space(3))) void*)(uint32_t)(uintptr_t)lds,
        16, 0, 0);
}

__device__ __forceinline__ unsigned short f2bf(float f) {
    unsigned int u = __float_as_uint(f);
    unsigned int r = (u + 0x7fffu + ((u >> 16) & 1u)) >> 16;
    return (unsigned short)r;
}

// ---------------- K1: bf16 cast + fused z@Wa / z@Wb per-block partials -----
// grid 1024 x 256; block handles 32 rows. thread: 4 cols (float4), 16 rows.
__global__ void __launch_bounds__(256) geo_k1(const float* __restrict__ x,
                                              unsigned short* __restrict__ xh,
                                              const float* __restrict__ Wa,
                                              const float* __restrict__ Wb,
                                              float* __restrict__ part) {
    const int tid  = threadIdx.x;
    const int c4   = (tid & 127) * 4;
    const int half = tid >> 7;
    const int r0   = blockIdx.x * 32 + half * 16;
    float4 s = {0.f, 0.f, 0.f, 0.f};
    for (int i = 0; i < 16; ++i) {
        const size_t base = (size_t)(r0 + i) * IN_DIM + c4;
        float4 v = *(const float4*)(x + base);
        s.x += v.x; s.y += v.y; s.z += v.z; s.w += v.w;
        ushort4 h;
        h.x = f2bf(v.x); h.y = f2bf(v.y); h.z = f2bf(v.z); h.w = f2bf(v.w);
        *(ushort4*)(xh + base) = h;
    }
    const float* wa = Wa + (size_t)c4 * 8;
    const float* wb = Wb + (size_t)c4 * 8;
    float av[8], bv[8];
#pragma unroll
    for (int r = 0; r < 8; ++r) {
        av[r] = s.x * wa[r] + s.y * wa[8 + r] + s.z * wa[16 + r] + s.w * wa[24 + r];
        bv[r] = s.x * wb[r] + s.y * wb[8 + r] + s.z * wb[16 + r] + s.w * wb[24 + r];
    }
#pragma unroll
    for (int off = 32; off; off >>= 1) {
#pragma unroll
        for (int r = 0; r < 8; ++r) {
            av[r] += __shfl_xor(av[r], off, 64);
            bv[r] += __shfl_xor(bv[r], off, 64);
        }
    }
    __shared__ float wred[4][16];
    const int lane = tid & 63, wave = tid >> 6;
    if (lane == 0) {
#pragma unroll
        for (int r = 0; r < 8; ++r) { wred[wave][r] = av[r]; wred[wave][8 + r] = bv[r]; }
    }
    __syncthreads();
    if (tid < 16)
        part[(size_t)blockIdx.x * 16 + tid] =
            wred[0][tid] + wred[1][tid] + wred[2][tid] + wred[3][tid];
}

// ---------------- K2: merged small algebra, 1 block, V in LDS --------------
__device__ __forceinline__ void mm16(float (*D)[16], float (*A)[16], float (*B)[16]) {
    const int tid = threadIdx.x;
    const int i = tid >> 4, j = tid & 15;
    float s = 0.f;
#pragma unroll
    for (int k = 0; k < 16; ++k) s += A[i][k] * B[k][j];
    __syncthreads();
    D[i][j] = s;
    __syncthreads();
}

__global__ void __launch_bounds__(256) geo_k2(const float* __restrict__ part,
                                              const float* __restrict__ La,
                                              const float* __restrict__ Ra,
                                              const float* __restrict__ Lb,
                                              const float* __restrict__ Rb,
                                              float* __restrict__ Vws,
                                              float* __restrict__ Lbp,
                                              float* __restrict__ VPws,
                                              float* __restrict__ RRws) {
    __shared__ float sV[IN_DIM][16];   // 32 KB
    __shared__ float sRb[IN_DIM][8];   // 16 KB
    __shared__ float red2[16][16];
    __shared__ float gs[16];
    __shared__ float G16[16][16], Jm[16][16];
    __shared__ float C2m[16][16], C3m[16][16], C4m[16][16];
    __shared__ float Cp[16][16], Cq[16][16];
    __shared__ float Pi[16][16], Xi[16][16], T1[16][16], T2[16][16], Ct[16][16];
    __shared__ float Zm[8][16], Em[8][16];
    const int tid = threadIdx.x;  // 256
    const int i = tid >> 4, j = tid & 15;

    // phase 0: reduce part[1024][16] -> gs (already scaled to the mean)
    {
        const int u = tid & 15, c = tid >> 4;  // 16 chunks x 64 rows
        float s = 0.f;
        for (int q = 0; q < 64; ++q) s += part[(size_t)(c * 64 + q) * 16 + u];
        red2[c][u] = s;
    }
    __syncthreads();
    if (tid < 16) {
        float s = 0.f;
#pragma unroll
        for (int c = 0; c < 16; ++c) s += red2[c][tid];
        gs[tid] = s * (1.0f / 32768.0f);
    }
    __syncthreads();

    // phase 1: build sV = [abar.*La | Ra], sRb, Lbp (global), Vws (global)
    for (int rr = 0; rr < 2; ++rr) {
        const int row = tid * 2 + rr;
#pragma unroll
        for (int r = 0; r < 8; ++r) {
            const float vl = gs[r] * La[row * 8 + r];
            const float vr = Ra[row * 8 + r];
            sV[row][r]     = vl;
            sV[row][8 + r] = vr;
            Vws[row * 16 + r]     = vl;
            Vws[row * 16 + 8 + r] = vr;
            sRb[row][r] = Rb[row * 8 + r];
            Lbp[row * 8 + r] = gs[8 + r] * Lb[row * 8 + r];
        }
    }
    __syncthreads();

    // phase 2: G16 = V^T V, Zm = Rb^T V (from LDS)
    {
        float s = 0.f;
        for (int k = 0; k < IN_DIM; ++k) s += sV[k][i] * sV[k][j];
        G16[i][j] = s;
        float jm = 0.f;
        if (i < 8 && j == i + 8) jm = 1.f;
        if (i >= 8 && j == i - 8) jm = -1.f;
        Jm[i][j] = jm;
    }
    if (tid < 128) {
        const int r = tid >> 4, u = tid & 15;
        float s = 0.f;
        for (int k = 0; k < IN_DIM; ++k) s += sRb[k][r] * sV[k][u];
        Zm[r][u] = s;
    }
    __syncthreads();

    // phase 3: RK4 core chain (16x16)
    mm16(T1, Jm, G16);  mm16(C2m, T1, Jm);
    mm16(T1, C2m, G16); mm16(C3m, T1, Jm);
    mm16(T1, C3m, G16); mm16(C4m, T1, Jm);

    const float h  = 0.125f;
    const float c1 = h, c2 = h * h * 0.5f, c3 = h * h * h * (1.f / 6.f),
                c4 = h * h * h * h * (1.f / 24.f);
    Cp[i][j] = c1 * Jm[i][j] + c2 * C2m[i][j] + c3 * C3m[i][j] + c4 * C4m[i][j];
    Cq[i][j] = c2 * Jm[i][j] + c3 * C2m[i][j] + c4 * C3m[i][j];
    Xi[i][j] = 0.f;
    __syncthreads();
    Pi[i][j] = Cp[i][j];
    __syncthreads();

    for (int it = 0; it < 7; ++it) {
        mm16(T1, Pi, G16);
        mm16(T2, T1, Cp);
        const float pij = Pi[i][j];
        Xi[i][j] += pij;
        Pi[i][j] = pij + Cp[i][j] + T2[i][j];
        __syncthreads();
    }

    mm16(T1, Cq, G16);
    mm16(T2, T1, Xi);
    Ct[i][j] = 8.f * Cq[i][j] + h * Xi[i][j] + T2[i][j];
    __syncthreads();

    // Em = Zm * Ct (8x16)
    if (tid < 128) {
        const int r = tid >> 4, u = tid & 15;
        float s = 0.f;
#pragma unroll
        for (int t = 0; t < 16; ++t) s += Zm[r][t] * Ct[t][u];
        Em[r][u] = s;
    }
    __syncthreads();

    // phase 4: VP = V @ Pi (512x16); RR[r][j] = Rb[j][r] + sum_u Em[r][u] V[j][u]
#pragma unroll
    for (int rr = 0; rr < 2; ++rr) {
        const int row = tid * 2 + rr;
        float v[16];
#pragma unroll
        for (int k = 0; k < 16; ++k) v[k] = sV[row][k];
#pragma unroll
        for (int u = 0; u < 16; ++u) {
            float s = 0.f;
#pragma unroll
            for (int k = 0; k < 16; ++k) s += v[k] * Pi[k][u];
            VPws[row * 16 + u] = s;
        }
#pragma unroll
        for (int r = 0; r < 8; ++r) {
            float s = sRb[row][r];
#pragma unroll
            for (int u = 0; u < 16; ++u) s += Em[r][u] * v[u];
            RRws[r * IN_DIM + row] = s;
        }
    }
}

// ---------------- K34: W row = U0 + (U0.VP) V^T + [0; Lbp RR] -> bf16 ------
__global__ void __launch_bounds__(256) geo_k34(const float* __restrict__ U0,
                                               const float* __restrict__ Vws,
                                               const float* __restrict__ VPws,
                                               const float* __restrict__ Lbp,
                                               const float* __restrict__ RRws,
                                               unsigned short* __restrict__ wh) {
    const int o   = blockIdx.x;
    const int tid = threadIdx.x;
    const int j0  = tid * 2;
    const float2 u0 = *(const float2*)(U0 + (size_t)o * IN_DIM + j0);

    const float* vpa = VPws + j0 * 16;
    const float* vpb = vpa + 16;
    float p[16];
#pragma unroll
    for (int u = 0; u < 16; ++u) p[u] = u0.x * vpa[u] + u0.y * vpb[u];
#pragma unroll
    for (int off = 32; off; off >>= 1) {
#pragma unroll
        for (int u = 0; u < 16; ++u) p[u] += __shfl_xor(p[u], off, 64);
    }
    __shared__ float wred[4][16];
    __shared__ float sY[16];
    const int lane = tid & 63, wave = tid >> 6;
    if (lane == 0) {
#pragma unroll
        for (int u = 0; u < 16; ++u) wred[wave][u] = p[u];
    }
    __syncthreads();
    if (tid < 16) sY[tid] = wred[0][tid] + wred[1][tid] + wred[2][tid] + wred[3][tid];
    __syncthreads();

    const float* va = Vws + j0 * 16;
    const float* vb = va + 16;
    float w0 = u0.x, w1 = u0.y;
#pragma unroll
    for (int u = 0; u < 16; ++u) {
        const float s = sY[u];
        w0 += s * va[u];
        w1 += s * vb[u];
    }
    if (o >= IN_DIM) {
        const int op = o - IN_DIM;
#pragma unroll
        for (int r = 0; r < 8; ++r) {
            const float lb = Lbp[op * 8 + r];
            w0 += lb * RRws[r * IN_DIM + j0];
            w1 += lb * RRws[r * IN_DIM + j0 + 1];
        }
    }
    ushort2 hv;
    hv.x = f2bf(w0); hv.y = f2bf(w1);
    *(ushort2*)(wh + (size_t)o * IN_DIM + j0) = hv;
}

// ---------------- K5: out = xh @ wh^T (bf16 MFMA, BK=64, swizzled) ---------
// 128x128 tile, BK=64 (8 k-iters), 256 threads, 4 waves x (4x4 MFMA of 16x16x32)
// Staging swizzle: LDS[row][c] holds global chunk c ^ (row&7) (16B chunks),
// applied on the GLOBAL address side so global_load_lds stays LDS-contiguous.
//
// XCD-aware remap (T1): 1-D grid of 2048 blocks. Dispatch round-robins
// consecutive block ids across the 8 XCDs, so we take xcd = bid & 7 and give
// each XCD a contiguous 32-mtile x 8-ntile slab, n-fastest:
//   - the 8 blocks sharing an A-tile run back-to-back on ONE XCD
//     -> A-tile (128 KB) stays L2-resident, A read once from HBM (was ~8x)
//   - the full B panel (1 MB bf16) is L2-resident per XCD
//   - concurrent A working set per XCD ~2.5 MB < 4 MB L2
__global__ void __launch_bounds__(256) geo_k5_gemm(const __hip_bfloat16* __restrict__ A,
                                                   const __hip_bfloat16* __restrict__ B,
                                                   float* __restrict__ C) {
    __shared__ __hip_bfloat16 As[128 * 64];   // 16 KB
    __shared__ __hip_bfloat16 Bs[128 * 64];   // 16 KB
    const int tid  = threadIdx.x;

    // bijective XCD remap: 2048 blocks = 8 xcds x (32 mtiles x 8 ntiles)
    const int bid  = blockIdx.x;
    const int xcd  = bid & 7;
    const int loc  = bid >> 3;                // 0..255, temporal order on this XCD
    const int mt   = xcd * 32 + (loc >> 3);   // 0..255
    const int nt   = loc & 7;                 // 0..7
    const int m0   = mt * 128;
    const int n0   = nt * 128;

    const int lane = tid & 63;
    const int wave = tid >> 6;
    const int wm   = (wave >> 1) * 64;
    const int wn   = (wave & 1) * 64;

    // staging: copy j of wave w -> region ri = w*4+j = rows [ri*8, ri*8+8)
    // lane covers row ri*8 + (lane>>3), global col chunk (lane&7)^(lane>>3)
    const int rowoff = lane >> 3;
    const int gcol   = ((lane & 7) ^ rowoff) * 8;   // swizzled global col (elems)
    const __hip_bfloat16* gA[4];
    const __hip_bfloat16* gB[4];
    char* lA[4];
    char* lB[4];
#pragma unroll
    for (int j2 = 0; j2 < 4; ++j2) {
        const int ri  = wave * 4 + j2;
        const int row = ri * 8 + rowoff;
        gA[j2] = A + (size_t)(m0 + row) * IN_DIM + gcol;
        gB[j2] = B + (size_t)(n0 + row) * IN_DIM + gcol;
        lA[j2] = (char*)As + ri * 1024 + lane * 16;
        lB[j2] = (char*)Bs + ri * 1024 + lane * 16;
    }

    f32x4 acc[4][4];
#pragma unroll
    for (int t = 0; t < 4; ++t)
#pragma unroll
        for (int s = 0; s < 4; ++s) acc[t][s] = (f32x4){0.f, 0.f, 0.f, 0.f};

    // fragment LDS byte offsets: row = w? + t*16 + (lane&15);
    // chunk = (h*4 + (lane>>4)) ^ (row&7), row&7 == lane&7 here
    const int frow = lane & 15;
    const int fsw  = lane & 7;
    const int fk   = lane >> 4;

    for (int kt = 0; kt < 8; ++kt) {
        const int k0 = kt * 64;
        __syncthreads();
#pragma unroll
        for (int j2 = 0; j2 < 4; ++j2) {
            async_copy16(lA[j2], gA[j2] + k0);
            async_copy16(lB[j2], gB[j2] + k0);
        }
        __syncthreads();

#pragma unroll
        for (int h = 0; h < 2; ++h) {
            frag_t af[4], bfr[4];
#pragma unroll
            for (int t = 0; t < 4; ++t)
                af[t] = *(const frag_t*)((const char*)As +
                        (size_t)(wm + t * 16 + frow) * 128 + (((h * 4 + fk) ^ fsw) * 16));
#pragma unroll
            for (int s = 0; s < 4; ++s)
                bfr[s] = *(const frag_t*)((const char*)Bs +
                        (size_t)(wn + s * 16 + frow) * 128 + (((h * 4 + fk) ^ fsw) * 16));
#pragma unroll
            for (int t = 0; t < 4; ++t)
#pragma unroll
                for (int s = 0; s < 4; ++s)
                    acc[t][s] = __builtin_amdgcn_mfma_f32_16x16x32_bf16(af[t], bfr[s], acc[t][s], 0, 0, 0);
        }
    }

    // C/D layout: col = lane&15, row = (lane>>4)*4 + v   [m89-verified]
    const int cm = m0 + wm + (lane >> 4) * 4;
    const int cn = n0 + wn + (lane & 15);
#pragma unroll
    for (int t = 0; t < 4; ++t)
#pragma unroll
        for (int s = 0; s < 4; ++s)
#pragma unroll
            for (int v = 0; v < 4; ++v)
                C[(size_t)(cm + t * 16 + v) * OUT_DIM + cn + s * 16] = acc[t][s][v];
}

extern "C" void kernel_launch(void* const* d_in, const int* in_sizes, int n_in,
                              void* d_out, int out_size, void* d_ws, size_t ws_size,
                              hipStream_t stream) {
    const float* x  = (const float*)d_in[0];
    const float* U0 = (const float*)d_in[1];
    const float* Wa = (const float*)d_in[2];
    const float* La = (const float*)d_in[3];
    const float* Ra = (const float*)d_in[4];
    const float* Wb = (const float*)d_in[5];
    const float* Lb = (const float*)d_in[6];
    const float* Rb = (const float*)d_in[7];
    float* out = (float*)d_out;

    char* ws = (char*)d_ws;
    unsigned short* xh  = (unsigned short*)(ws);             // 33,554,432 B
    unsigned short* wh  = (unsigned short*)(ws + 33554432);  //  1,048,576 B
    float* part = (float*)(ws + 34603008);                   //     65,536 B
    float* Vws  = (float*)(ws + 34668544);                   //     32,768 B
    float* Lbp  = (float*)(ws + 34701312);                   //     16,384 B
    float* RRws = (float*)(ws + 34717696);                   //     16,384 B
    float* VPws = (float*)(ws + 34734080);                   //     32,768 B

    geo_k1<<<1024, 256, 0, stream>>>(x, xh, Wa, Wb, part);
    geo_k2<<<1, 256, 0, stream>>>(part, La, Ra, Lb, Rb, Vws, Lbp, VPws, RRws);
    geo_k34<<<1024, 256, 0, stream>>>(U0, Vws, VPws, Lbp, RRws, wh);
    geo_k5_gemm<<<2048, 256, 0, stream>>>((const __hip_bfloat16*)xh,
                                          (const __hip_bfloat16*)wh, out);
}